// Round 3
// baseline (283.463 us; speedup 1.0000x reference)
//
#include <hip/hip_runtime.h>
#include <hip/hip_bf16.h>
#include <stdint.h>

typedef unsigned short u16;
typedef __attribute__((ext_vector_type(8))) short short8;
typedef __attribute__((ext_vector_type(4))) float f32x4;

#define NB 2
#define NN 2048
#define ND 1024
#define NH 16
#define NR 32
#define NM (NB*NN)      // 4096 rows
#define NHR 512         // h*r
#define NQKV 1536       // 3*h*r

static __device__ __forceinline__ u16 f2bf(float f) {
  union { float f; uint32_t u; } v; v.f = f;
  uint32_t r = v.u + 0x7fffu + ((v.u >> 16) & 1u);
  return (u16)(r >> 16);
}

typedef __attribute__((address_space(1))) unsigned int as1_u32;
typedef __attribute__((address_space(3))) unsigned int as3_u32;

// async global->LDS, 16B per lane. LDS dest is wave-uniform base + lane*16
// (m104/m108) -- all call sites pass lane-consecutive 16B destinations.
static __device__ __forceinline__ void async_copy16(void* lds, const void* g) {
  __builtin_amdgcn_global_load_lds((as1_u32*)(uintptr_t)g,
                                   (as3_u32*)(uint32_t)(uintptr_t)lds,
                                   16, 0, 0);
}

// ---------------------------------------------------------------------------
// K0: fp32 -> bf16 cast, 8 elements/thread (two float4 loads, one 16B store).
// ---------------------------------------------------------------------------
__global__ void cast_f32_bf16(const float* __restrict__ in, u16* __restrict__ o,
                              int n8) {
  int i = blockIdx.x * 256 + threadIdx.x;
  if (i >= n8) return;
  const float4* p = (const float4*)in + (size_t)i * 2;
  float4 a = p[0], b = p[1];
  short8 v;
  v[0] = f2bf(a.x); v[1] = f2bf(a.y); v[2] = f2bf(a.z); v[3] = f2bf(a.w);
  v[4] = f2bf(b.x); v[5] = f2bf(b.y); v[6] = f2bf(b.z); v[7] = f2bf(b.w);
  *((short8*)o + i) = v;
}

// ---------------------------------------------------------------------------
// K1: WcT[col][i] = sum_k W_w[head*64+k][i] * U[k][rr],  col = w*512+head*32+rr
// fp32 inputs, fp32 accumulate, bf16 out. Q columns (w==0) scaled by 1/8.
// ---------------------------------------------------------------------------
__global__ void build_wct(const float* __restrict__ Wq, const float* __restrict__ Wk,
                          const float* __restrict__ Wv, const float* __restrict__ U,
                          u16* __restrict__ WcT) {
  int flat = blockIdx.x * 256 + threadIdx.x;     // NQKV*ND threads
  int i = flat & (ND - 1);
  int col = flat >> 10;
  int w = col >> 9;
  int ch = col & 511;
  int head = ch >> 5;
  int rr = ch & 31;
  const float* W = (w == 0) ? Wq : (w == 1 ? Wk : Wv);
  float acc = 0.f;
  #pragma unroll 8
  for (int kk = 0; kk < 64; ++kk)
    acc += W[(head * 64 + kk) * ND + i] * U[kk * 32 + rr];
  if (w == 0) acc *= 0.125f;
  WcT[(size_t)col * ND + i] = f2bf(acc);
}

// ---------------------------------------------------------------------------
// Generic MFMA GEMM:  C[M x Ncol] = A[M x K] * BT[Ncol x K]^T, bf16 in, fp32 acc.
// 128x128 tile / block (4 waves, each 64x64 -> 4x4 MFMA tiles), BK=64,
// global_load_lds width-16 staging, XOR-swizzled LDS (16B chunk ^= row&7).
// EPI=0: fp32 row-major store to fo (ld = 1024).
// EPI=1: QKV scatter (bf16): q,k -> [B,h,N,r]; v -> transposed [B,h,r,N].
// ---------------------------------------------------------------------------
template<int EPI>
__global__ __launch_bounds__(256, 2)
void gemm_bt(const u16* __restrict__ A, int lda,
             const u16* __restrict__ BT, int ldb, int K,
             u16* __restrict__ o0, u16* __restrict__ o1, u16* __restrict__ o2,
             float* __restrict__ fo) {
  __shared__ __align__(16) u16 lA[128 * 64];
  __shared__ __align__(16) u16 lB[128 * 64];
  const int tid = threadIdx.x;
  const int lane = tid & 63, quad = lane >> 4, l16 = lane & 15;
  const int wave = tid >> 6;
  const int wm = (wave >> 1) * 64, wn = (wave & 1) * 64;
  const int rowBase = blockIdx.y * 128, colBase = blockIdx.x * 128;

  f32x4 acc[4][4];
  #pragma unroll
  for (int i = 0; i < 4; ++i)
    #pragma unroll
    for (int j = 0; j < 4; ++j)
      acc[i][j] = (f32x4){0.f, 0.f, 0.f, 0.f};

  for (int kt = 0; kt < K; kt += 64) {
    #pragma unroll
    for (int it = 0; it < 4; ++it) {
      const int cid = it * 256 + tid;          // 1024 16B-chunks per tile
      const int row = cid >> 3, pc = cid & 7;  // pc = LDS chunk slot
      const int gc = pc ^ (row & 7);           // source global chunk
      async_copy16(&lA[cid * 8], &A[(size_t)(rowBase + row) * lda + kt + gc * 8]);
      async_copy16(&lB[cid * 8], &BT[(size_t)(colBase + row) * ldb + kt + gc * 8]);
    }
    __syncthreads();
    #pragma unroll
    for (int ks = 0; ks < 64; ks += 32) {
      short8 fa[4], fb[4];
      #pragma unroll
      for (int t = 0; t < 4; ++t) {
        const int ra = wm + t * 16 + l16;
        const int pa = ((ks >> 3) + quad) ^ (ra & 7);
        fa[t] = *(const short8*)&lA[ra * 64 + pa * 8];
        const int rb = wn + t * 16 + l16;
        const int pb = ((ks >> 3) + quad) ^ (rb & 7);
        fb[t] = *(const short8*)&lB[rb * 64 + pb * 8];
      }
      #pragma unroll
      for (int mt = 0; mt < 4; ++mt)
        #pragma unroll
        for (int nt = 0; nt < 4; ++nt)
          acc[mt][nt] = __builtin_amdgcn_mfma_f32_16x16x32_bf16(
              fa[mt], fb[nt], acc[mt][nt], 0, 0, 0);
    }
    __syncthreads();
  }

  // epilogue: C/D layout col = lane&15, row = quad*4 + reg  [m89/m91 verified]
  #pragma unroll
  for (int mt = 0; mt < 4; ++mt) {
    const int gr0 = rowBase + wm + mt * 16 + quad * 4;
    #pragma unroll
    for (int nt = 0; nt < 4; ++nt) {
      const int c = colBase + wn + nt * 16 + l16;
      #pragma unroll
      for (int j = 0; j < 4; ++j) {
        const float v = acc[mt][nt][j];
        const int row = gr0 + j;
        if (EPI == 0) {
          fo[(size_t)row * 1024 + c] = v;      // fp32 output
        } else {
          const int b = row >> 11, n = row & (NN - 1);
          const int w = c >> 9, ch = c & 511, head = ch >> 5, rr = ch & 31;
          if (w == 0)
            o0[(size_t)(((b * NH + head) * NN + n)) * NR + rr] = f2bf(v);
          else if (w == 1)
            o1[(size_t)(((b * NH + head) * NN + n)) * NR + rr] = f2bf(v);
          else  // v stored transposed: vt[b,h,rr,n]
            o2[(size_t)((b * NH + head) * NR + rr) * NN + n] = f2bf(v);
        }
      }
    }
  }
}

// ---------------------------------------------------------------------------
// K3: causal flash attention. q,k: [B,h,N,r] bf16 (q pre-scaled), vt: [B,h,r,N].
// 1 wave per 16 q-rows, 64 q-rows per block, per-wave LDS P round-trip.
// Alibi bias is identically 0 on the causal support; masked tiles skipped.
// z out: [B,N,h*r] bf16.
// ---------------------------------------------------------------------------
__global__ __launch_bounds__(256, 2)
void flash_attn(const u16* __restrict__ q, const u16* __restrict__ k,
                const u16* __restrict__ vt, u16* __restrict__ z) {
  __shared__ __align__(16) u16 px[4][16 * 40];   // per-wave P scratch, row stride 40
  const int bh = blockIdx.y;                     // 0..31
  const int b = bh >> 4, head = bh & 15;
  const int tid = threadIdx.x;
  const int lane = tid & 63, quad = lane >> 4, l16 = lane & 15;
  const int wave = tid >> 6;
  const int qbase = blockIdx.x * 64 + wave * 16;

  const u16* qp = q  + (size_t)bh * NN * NR;
  const u16* kp = k  + (size_t)bh * NN * NR;
  const u16* vp = vt + (size_t)bh * NR * NN;
  u16* myp = &px[wave][0];

  // A-frag of Q tile: A[m=lane&15][kdim=quad*8+j]
  const short8 aq = *(const short8*)&qp[(size_t)(qbase + l16) * NR + quad * 8];

  float mi[4], li[4];
  f32x4 z0 = (f32x4){0.f,0.f,0.f,0.f}, z1 = (f32x4){0.f,0.f,0.f,0.f};
  #pragma unroll
  for (int j = 0; j < 4; ++j) { mi[j] = -1e30f; li[j] = 0.f; }

  const int nkt = (qbase + 15) / 32 + 1;         // causal: key tiles covering m <= n
  for (int kt = 0; kt < nkt; ++kt) {
    const int m0 = kt * 32;
    const short8 bk0 = *(const short8*)&kp[(size_t)(m0 + l16) * NR + quad * 8];
    const short8 bk1 = *(const short8*)&kp[(size_t)(m0 + 16 + l16) * NR + quad * 8];
    const f32x4 zero = (f32x4){0.f,0.f,0.f,0.f};
    f32x4 s0 = __builtin_amdgcn_mfma_f32_16x16x32_bf16(aq, bk0, zero, 0, 0, 0);
    f32x4 s1 = __builtin_amdgcn_mfma_f32_16x16x32_bf16(aq, bk1, zero, 0, 0, 0);

    #pragma unroll
    for (int j = 0; j < 4; ++j) {
      const int n = qbase + quad * 4 + j;        // this element's query row
      if (m0 + l16 > n)      s0[j] = -1e30f;     // causal mask (== mask + alibi)
      if (m0 + 16 + l16 > n) s1[j] = -1e30f;
      float rmax = fmaxf(s0[j], s1[j]);
      #pragma unroll
      for (int off = 1; off < 16; off <<= 1)
        rmax = fmaxf(rmax, __shfl_xor(rmax, off));
      const float mnew = fmaxf(mi[j], rmax);
      const float alpha = __expf(mi[j] - mnew);
      mi[j] = mnew;
      const float p0 = __expf(s0[j] - mnew);
      const float p1 = __expf(s1[j] - mnew);
      float rs = p0 + p1;
      #pragma unroll
      for (int off = 1; off < 16; off <<= 1)
        rs += __shfl_xor(rs, off);
      li[j] = li[j] * alpha + rs;
      z0[j] *= alpha;
      z1[j] *= alpha;
      // C-layout -> LDS [16 rows][32 keys], row stride 40 shorts (80B, 16B-aligned)
      myp[(quad * 4 + j) * 40 + l16]      = f2bf(p0);
      myp[(quad * 4 + j) * 40 + 16 + l16] = f2bf(p1);
    }
    // Drain ds_writes; cross-lane dep is invisible to per-thread alias analysis.
    asm volatile("s_waitcnt lgkmcnt(0)" ::: "memory");
    const short8 ap = *(const short8*)&myp[l16 * 40 + quad * 8];
    asm volatile("" ::: "memory");  // keep next-iter ds_writes below this read
    const short8 bv0 = *(const short8*)&vp[(size_t)l16 * NN + m0 + quad * 8];
    const short8 bv1 = *(const short8*)&vp[(size_t)(16 + l16) * NN + m0 + quad * 8];
    z0 = __builtin_amdgcn_mfma_f32_16x16x32_bf16(ap, bv0, z0, 0, 0, 0);
    z1 = __builtin_amdgcn_mfma_f32_16x16x32_bf16(ap, bv1, z1, 0, 0, 0);
  }

  #pragma unroll
  for (int j = 0; j < 4; ++j) {
    const int n = qbase + quad * 4 + j;
    const float inv = 1.f / li[j];
    u16* zr = z + (size_t)(b * NN + n) * NHR + head * NR;
    zr[l16]      = f2bf(z0[j] * inv);
    zr[16 + l16] = f2bf(z1[j] * inv);
  }
}

// ---------------------------------------------------------------------------
extern "C" void kernel_launch(void* const* d_in, const int* in_sizes, int n_in,
                              void* d_out, int out_size, void* d_ws, size_t ws_size,
                              hipStream_t stream) {
  const float* x     = (const float*)d_in[0];
  // d_in[1] = mask: causal additive mask, handled analytically (unused)
  const float* Wq    = (const float*)d_in[2];
  const float* Wk    = (const float*)d_in[3];
  const float* Wv    = (const float*)d_in[4];
  const float* U     = (const float*)d_in[5];
  const float* Wproj = (const float*)d_in[6];
  // d_in[7] = rel_bias_tokens (N, alibi path): dist==0 on causal support (unused)
  float* out = (float*)d_out;

  // Workspace layout (24 MB), u16 units:
  //   [0,8MB)  xb  (bf16 x, 4M) -- dead after gemm<1>; z (4MB) aliases it
  //   [8,9MB)  Wpb (bf16 Wproj, 512K)
  //   [9,12MB) WcT (1536x1024)
  //   [12,24MB) q, kk, vt (2M u16 each)
  u16* ws  = (u16*)d_ws;
  u16* xb  = ws;
  u16* z   = ws;                                   // alias xb (see ordering)
  u16* Wpb = ws + (size_t)4 * 1024 * 1024;
  u16* WcT = Wpb + (size_t)512 * 1024;
  u16* q   = ws + (size_t)6 * 1024 * 1024;
  u16* kk  = q  + (size_t)NB * NH * NN * NR;
  u16* vt  = kk + (size_t)NB * NH * NN * NR;

  cast_f32_bf16<<<(NM * ND / 8 + 255) / 256, 256, 0, stream>>>(x, xb, NM * ND / 8);
  cast_f32_bf16<<<(ND * NHR / 8 + 255) / 256, 256, 0, stream>>>(Wproj, Wpb, ND * NHR / 8);
  build_wct<<<(NQKV * ND) / 256, 256, 0, stream>>>(Wq, Wk, Wv, U, WcT);
  gemm_bt<1><<<dim3(NQKV / 128, NM / 128), 256, 0, stream>>>(
      xb, ND, WcT, ND, ND, q, kk, vt, nullptr);
  flash_attn<<<dim3(NN / 64, NB * NH), 256, 0, stream>>>(q, kk, vt, z);
  gemm_bt<0><<<dim3(ND / 128, NM / 128), 256, 0, stream>>>(
      z, NHR, Wpb, NHR, NHR, nullptr, nullptr, nullptr, out);
}